// Round 3
// baseline (121.065 us; speedup 1.0000x reference)
//
#include <hip/hip_runtime.h>
#include <cstdint>

// AttentionFlow — fully fused flash-style MFMA version.
// B=8, T=2048, I=512, D=512. Output (B,T,4D) fp32.
//
//  1. rowdot(q):   sq[b,i] = <q,w_q>+b_q                          (ws)
//  2. fused_attn:  per 64-row t-tile: S = (c.*w_cq)@q^T + sc+sq+b_cq
//                  (sc computed inline during staging), exact softmax_i in
//                  registers, P->LDS bf16, O = P@q, epilogue writes
//                  out slots [c | c2q | c*c2q | -]; mrow -> ws
//  3. t_softmax:   bw = softmax_t(mrow)                           (ws)
//  4. q2c split-K: q2c[b,d] = sum_t bw*c                          (ws)
//  5. slot3:       out[...,3D:4D] = c*q2c

constexpr int kB = 8;
constexpr int kT = 2048;
constexpr int kI = 512;
constexpr int kD = 512;
constexpr int kW = 4 * kD;

constexpr int kSplit = 16;
constexpr int kTchunk = kT / kSplit;

using f32x4  = __attribute__((ext_vector_type(4))) float;
using bf16x4 = __attribute__((ext_vector_type(4))) __bf16;
using bf16x8 = __attribute__((ext_vector_type(8))) __bf16;

// LDS layout (bytes), total 124160:
//  [0,      5120)   phase1 lA   (64 rows x 80)           } aliased by
//  [5120,  46080)   phase1 lB   (512 rows x 80)          } lP after phase 1
//  [0,     81920)   phase2 lP   (16 chunks x 64 rows x 80)
//  [81920,122880)   phase2 lBT  (512 rows x 80)
//  [122880,123136)  scrow (64 f32)
//  [123136,124160)  red   (4*64 f32)
constexpr int LDS_LB   = 5120;
constexpr int LDS_LBT  = 81920;
constexpr int LDS_SC   = 122880;
constexpr int LDS_RED  = 123136;
constexpr int LDS_SIZE = 124160;

__device__ __forceinline__ float wave_max(float v) {
#pragma unroll
  for (int off = 32; off > 0; off >>= 1) v = fmaxf(v, __shfl_xor(v, off, 64));
  return v;
}
__device__ __forceinline__ float wave_sum(float v) {
#pragma unroll
  for (int off = 32; off > 0; off >>= 1) v += __shfl_xor(v, off, 64);
  return v;
}

__global__ __launch_bounds__(256) void rowdot_kernel(
    const float* __restrict__ x, const float* __restrict__ w,
    const float* __restrict__ bias, float* __restrict__ out) {
  const int wave = (blockIdx.x * 256 + threadIdx.x) >> 6;
  const int lane = threadIdx.x & 63;
  const float* row = x + (size_t)wave * kD;
  float s = 0.f;
#pragma unroll
  for (int j = 0; j < kD / 64; ++j) s += row[lane + j * 64] * w[lane + j * 64];
  s = wave_sum(s);
  if (lane == 0) out[wave] = s + bias[0];
}

__global__ __launch_bounds__(512, 2) void fused_attn(
    const float* __restrict__ c, const float* __restrict__ q,
    const float* __restrict__ w_cq, const float* __restrict__ w_c,
    const float* __restrict__ b_c, const float* __restrict__ b_cq,
    const float* __restrict__ sq, float* __restrict__ out,
    float* __restrict__ mrow) {
  __shared__ __align__(16) char smem[LDS_SIZE];
  char* lA = smem;
  char* lB = smem + LDS_LB;
  char* lP = smem;
  char* lBT = smem + LDS_LBT;
  float* scrow = (float*)(smem + LDS_SC);
  float* red = (float*)(smem + LDS_RED);

  const int b = blockIdx.y;
  const int t0 = blockIdx.x * 64;
  const int tid = threadIdx.x;
  const int lane = tid & 63;
  const int w = tid >> 6;         // 0..7
  const int wm = w >> 2;          // 0..1 -> rows wm*32..+32
  const int wn = w & 3;           // 0..3 -> cols wn*128..+128
  const int lr = lane & 15, lg = lane >> 4;

  const int arow = tid >> 3;      // 0..63
  const int acg = (tid & 7) * 4;  // 0,4,...,28
  const float* Cb = c + ((size_t)(b * kT + t0)) * kD;
  const float* Qb = q + ((size_t)b * kI) * kD;

  // ---------------- Phase 1: S = (c.*w_cq) @ q^T (K = d = 512) -----------
  f32x4 acc[2][8] = {};
  float scp = 0.f;  // partial <c_row, w_c> for row=arow, cols acg+32k

  for (int k0 = 0; k0 < kD; k0 += 32) {
    const f32x4 cv = *(const f32x4*)(Cb + (size_t)arow * kD + k0 + acg);
    const f32x4 wq4 = *(const f32x4*)(w_cq + k0 + acg);
    const f32x4 wc4 = *(const f32x4*)(w_c + k0 + acg);
    f32x4 qv[8];
#pragma unroll
    for (int s = 0; s < 8; ++s)
      qv[s] = *(const f32x4*)(Qb + (size_t)(arow + s * 64) * kD + k0 + acg);

    scp += cv.x * wc4.x + cv.y * wc4.y + cv.z * wc4.z + cv.w * wc4.w;
    const f32x4 vw = cv * wq4;

    __syncthreads();
    bf16x4 bv = {(__bf16)vw.x, (__bf16)vw.y, (__bf16)vw.z, (__bf16)vw.w};
    *(bf16x4*)(lA + arow * 80 + acg * 2) = bv;
#pragma unroll
    for (int s = 0; s < 8; ++s) {
      bf16x4 bu = {(__bf16)qv[s].x, (__bf16)qv[s].y, (__bf16)qv[s].z,
                   (__bf16)qv[s].w};
      *(bf16x4*)(lB + (arow + s * 64) * 80 + acg * 2) = bu;
    }
    __syncthreads();

    bf16x8 af[2];
#pragma unroll
    for (int m = 0; m < 2; ++m)
      af[m] = *(const bf16x8*)(lA + (wm * 32 + m * 16 + lr) * 80 + lg * 16);
#pragma unroll
    for (int n = 0; n < 8; ++n) {
      bf16x8 bfv = *(const bf16x8*)(lB + (wn * 128 + n * 16 + lr) * 80 + lg * 16);
      acc[0][n] = __builtin_amdgcn_mfma_f32_16x16x32_bf16(af[0], bfv, acc[0][n], 0, 0, 0);
      acc[1][n] = __builtin_amdgcn_mfma_f32_16x16x32_bf16(af[1], bfv, acc[1][n], 0, 0, 0);
    }
  }

  // sc reduce: 8 threads (consecutive lanes) share a row
  scp += __shfl_xor(scp, 1, 64);
  scp += __shfl_xor(scp, 2, 64);
  scp += __shfl_xor(scp, 4, 64);
  if ((tid & 7) == 0) scrow[arow] = scp + b_c[0];
  __syncthreads();

  // biases
  const float bq = b_cq[0];
  float sqv[8];
#pragma unroll
  for (int n = 0; n < 8; ++n)
    sqv[n] = sq[b * kI + wn * 128 + n * 16 + lr];
  float scr[2][4];
#pragma unroll
  for (int m = 0; m < 2; ++m)
#pragma unroll
    for (int r = 0; r < 4; ++r)
      scr[m][r] = scrow[wm * 32 + m * 16 + lg * 4 + r] + bq;
#pragma unroll
  for (int m = 0; m < 2; ++m)
#pragma unroll
    for (int n = 0; n < 8; ++n)
#pragma unroll
      for (int r = 0; r < 4; ++r) acc[m][n][r] += scr[m][r] + sqv[n];

  // ---------------- exact softmax over i (512) ---------------------------
  float mx[2][4];
#pragma unroll
  for (int m = 0; m < 2; ++m)
#pragma unroll
    for (int r = 0; r < 4; ++r) {
      float v = acc[m][0][r];
#pragma unroll
      for (int n = 1; n < 8; ++n) v = fmaxf(v, acc[m][n][r]);
#pragma unroll
      for (int off = 1; off <= 8; off <<= 1) v = fmaxf(v, __shfl_xor(v, off, 64));
      mx[m][r] = v;
    }
  if (lr == 0) {
#pragma unroll
    for (int m = 0; m < 2; ++m)
#pragma unroll
      for (int r = 0; r < 4; ++r)
        red[wn * 64 + wm * 32 + m * 16 + lg * 4 + r] = mx[m][r];
  }
  __syncthreads();
#pragma unroll
  for (int m = 0; m < 2; ++m)
#pragma unroll
    for (int r = 0; r < 4; ++r) {
      const int rw = wm * 32 + m * 16 + lg * 4 + r;
      mx[m][r] = fmaxf(fmaxf(red[rw], red[64 + rw]),
                       fmaxf(red[128 + rw], red[192 + rw]));
    }
  if (wn == 0 && lr == 0) {
#pragma unroll
    for (int m = 0; m < 2; ++m)
#pragma unroll
      for (int r = 0; r < 4; ++r)
        mrow[b * kT + t0 + wm * 32 + m * 16 + lg * 4 + r] = mx[m][r];
  }

  float sm[2][4] = {};
#pragma unroll
  for (int m = 0; m < 2; ++m)
#pragma unroll
    for (int n = 0; n < 8; ++n)
#pragma unroll
      for (int r = 0; r < 4; ++r) {
        const float p = __expf(acc[m][n][r] - mx[m][r]);
        acc[m][n][r] = p;
        sm[m][r] += p;
      }
#pragma unroll
  for (int m = 0; m < 2; ++m)
#pragma unroll
    for (int r = 0; r < 4; ++r)
#pragma unroll
      for (int off = 1; off <= 8; off <<= 1)
        sm[m][r] += __shfl_xor(sm[m][r], off, 64);
  __syncthreads();  // guard red reuse (also separates lB reads from lP writes)
  if (lr == 0) {
#pragma unroll
    for (int m = 0; m < 2; ++m)
#pragma unroll
      for (int r = 0; r < 4; ++r)
        red[wn * 64 + wm * 32 + m * 16 + lg * 4 + r] = sm[m][r];
  }
  __syncthreads();
  float inv[2][4];
#pragma unroll
  for (int m = 0; m < 2; ++m)
#pragma unroll
    for (int r = 0; r < 4; ++r) {
      const int rw = wm * 32 + m * 16 + lg * 4 + r;
      inv[m][r] = 1.f / (red[rw] + red[64 + rw] + red[128 + rw] + red[192 + rw]);
    }

  // ---------------- P (bf16) -> LDS, k-chunked [kk][row][32] -------------
#pragma unroll
  for (int m = 0; m < 2; ++m)
#pragma unroll
    for (int r = 0; r < 4; ++r) {
      const int trow = wm * 32 + m * 16 + lg * 4 + r;
#pragma unroll
      for (int n = 0; n < 8; ++n) {
        const int icol = wn * 128 + n * 16 + lr;
        const int kk = icol >> 5, kc = icol & 31;
        *(__bf16*)(lP + kk * 5120 + trow * 80 + kc * 2) =
            (__bf16)(acc[m][n][r] * inv[m][r]);
      }
    }
  __syncthreads();

  // ---------------- Phase 2: O = P @ q (K = i = 512) ---------------------
  f32x4 o[2][8] = {};
  const int bi = (tid & 7) * 4;   // i offset within 32-chunk
  const int bd = (tid >> 3) * 8;  // d column base (8 cols per thread)
  for (int k0 = 0; k0 < kI; k0 += 32) {
    f32x4 r0a = *(const f32x4*)(Qb + (size_t)(k0 + bi + 0) * kD + bd);
    f32x4 r0b = *(const f32x4*)(Qb + (size_t)(k0 + bi + 0) * kD + bd + 4);
    f32x4 r1a = *(const f32x4*)(Qb + (size_t)(k0 + bi + 1) * kD + bd);
    f32x4 r1b = *(const f32x4*)(Qb + (size_t)(k0 + bi + 1) * kD + bd + 4);
    f32x4 r2a = *(const f32x4*)(Qb + (size_t)(k0 + bi + 2) * kD + bd);
    f32x4 r2b = *(const f32x4*)(Qb + (size_t)(k0 + bi + 2) * kD + bd + 4);
    f32x4 r3a = *(const f32x4*)(Qb + (size_t)(k0 + bi + 3) * kD + bd);
    f32x4 r3b = *(const f32x4*)(Qb + (size_t)(k0 + bi + 3) * kD + bd + 4);
    __syncthreads();
#pragma unroll
    for (int j = 0; j < 4; ++j) {
      bf16x4 col = {(__bf16)r0a[j], (__bf16)r1a[j], (__bf16)r2a[j], (__bf16)r3a[j]};
      *(bf16x4*)(lBT + (bd + j) * 80 + bi * 2) = col;
    }
#pragma unroll
    for (int j = 0; j < 4; ++j) {
      bf16x4 col = {(__bf16)r0b[j], (__bf16)r1b[j], (__bf16)r2b[j], (__bf16)r3b[j]};
      *(bf16x4*)(lBT + (bd + 4 + j) * 80 + bi * 2) = col;
    }
    __syncthreads();

    bf16x8 af2[2];
#pragma unroll
    for (int m = 0; m < 2; ++m)
      af2[m] = *(const bf16x8*)(lP + (k0 >> 5) * 5120 +
                                (wm * 32 + m * 16 + lr) * 80 + lg * 16);
#pragma unroll
    for (int n = 0; n < 8; ++n) {
      bf16x8 bfv = *(const bf16x8*)(lBT + (wn * 128 + n * 16 + lr) * 80 + lg * 16);
      o[0][n] = __builtin_amdgcn_mfma_f32_16x16x32_bf16(af2[0], bfv, o[0][n], 0, 0, 0);
      o[1][n] = __builtin_amdgcn_mfma_f32_16x16x32_bf16(af2[1], bfv, o[1][n], 0, 0, 0);
    }
  }

  // ---------------- epilogue: slots [c | c2q | c*c2q] --------------------
#pragma unroll
  for (int m = 0; m < 2; ++m)
#pragma unroll
    for (int r = 0; r < 4; ++r) {
      const int t = t0 + wm * 32 + m * 16 + lg * 4 + r;
      const size_t rb = (size_t)(b * kT + t);
      const float* crow = c + rb * kD;
      float* orow = out + rb * kW;
#pragma unroll
      for (int n = 0; n < 8; ++n) {
        const int d = wn * 128 + n * 16 + lr;
        const float cvv = crow[d];
        const float pv = o[m][n][r];
        orow[d] = cvv;
        orow[kD + d] = pv;
        orow[2 * kD + d] = cvv * pv;
      }
    }
}

__global__ __launch_bounds__(1024) void t_softmax_kernel(
    const float* __restrict__ mrow, float* __restrict__ bw) {
  const int b = blockIdx.x;
  const int tid = threadIdx.x;
  const float v0 = mrow[b * kT + tid], v1 = mrow[b * kT + tid + 1024];
  __shared__ float redm[16];
  __shared__ float reds[16];
  const int wave = tid >> 6, lane = tid & 63;
  float mx = wave_max(fmaxf(v0, v1));
  if (lane == 0) redm[wave] = mx;
  __syncthreads();
  mx = redm[0];
#pragma unroll
  for (int i = 1; i < 16; ++i) mx = fmaxf(mx, redm[i]);
  const float e0 = __expf(v0 - mx), e1 = __expf(v1 - mx);
  float sm = wave_sum(e0 + e1);
  if (lane == 0) reds[wave] = sm;
  __syncthreads();
  sm = 0.f;
#pragma unroll
  for (int i = 0; i < 16; ++i) sm += reds[i];
  const float inv = 1.f / sm;
  bw[b * kT + tid] = e0 * inv;
  bw[b * kT + tid + 1024] = e1 * inv;
}

__global__ __launch_bounds__(256) void q2c_part_kernel(
    const float* __restrict__ c, const float* __restrict__ bw,
    float* __restrict__ part) {
  const int b = blockIdx.y;
  const int sp = blockIdx.x;
  const int tid = threadIdx.x;
  const int d0 = tid, d1 = tid + 256;
  float a0 = 0.f, a1 = 0.f;
  const int tbase = sp * kTchunk;
  for (int t = 0; t < kTchunk; ++t) {
    const float w = bw[b * kT + tbase + t];
    const float* crow = c + ((size_t)b * kT + tbase + t) * kD;
    a0 += w * crow[d0];
    a1 += w * crow[d1];
  }
  part[((size_t)b * kSplit + sp) * kD + d0] = a0;
  part[((size_t)b * kSplit + sp) * kD + d1] = a1;
}

__global__ __launch_bounds__(512) void q2c_reduce_kernel(
    const float* __restrict__ part, float* __restrict__ q2c) {
  const int b = blockIdx.x;
  const int d = threadIdx.x;
  float s = 0.f;
#pragma unroll
  for (int p = 0; p < kSplit; ++p) s += part[((size_t)b * kSplit + p) * kD + d];
  q2c[b * kD + d] = s;
}

__global__ __launch_bounds__(128) void slot3_kernel(
    const float* __restrict__ c, const float* __restrict__ q2c,
    float* __restrict__ out) {
  const int row = blockIdx.x;  // b*kT + t
  const int b = row >> 11;
  const int x4 = threadIdx.x * 4;
  f32x4 cv = *(const f32x4*)(c + (size_t)row * kD + x4);
  f32x4 qc = *(const f32x4*)(q2c + b * kD + x4);
  *(f32x4*)(out + (size_t)row * kW + 3 * kD + x4) = cv * qc;
}

extern "C" void kernel_launch(void* const* d_in, const int* in_sizes, int n_in,
                              void* d_out, int out_size, void* d_ws, size_t ws_size,
                              hipStream_t stream) {
  const float* c    = (const float*)d_in[0];
  const float* q    = (const float*)d_in[1];
  const float* w_c  = (const float*)d_in[2];
  const float* b_c  = (const float*)d_in[3];
  const float* w_q  = (const float*)d_in[4];
  const float* b_q  = (const float*)d_in[5];
  const float* w_cq = (const float*)d_in[6];
  const float* b_cq = (const float*)d_in[7];
  float* out = (float*)d_out;
  float* ws = (float*)d_ws;

  // ws layout (floats): sq 4096 | mrow 16384 | bw 16384 | part 65536 | q2c 4096
  float* sq   = ws;
  float* mrow = sq + kB * kI;
  float* bw   = mrow + kB * kT;
  float* part = bw + kB * kT;
  float* q2c  = part + (size_t)kB * kSplit * kD;

  rowdot_kernel<<<kB * kI / 4, 256, 0, stream>>>(q, w_q, b_q, sq);

  dim3 gf(kT / 64, kB);
  fused_attn<<<gf, 512, 0, stream>>>(c, q, w_cq, w_c, b_c, b_cq, sq, out, mrow);

  t_softmax_kernel<<<kB, 1024, 0, stream>>>(mrow, bw);
  dim3 gq(kSplit, kB);
  q2c_part_kernel<<<gq, 256, 0, stream>>>(c, bw, part);
  q2c_reduce_kernel<<<kB, 512, 0, stream>>>(part, q2c);

  slot3_kernel<<<kB * kT, 128, 0, stream>>>(c, q2c, out);
}